// Round 14
// baseline (521.225 us; speedup 1.0000x reference)
//
#include <hip/hip_runtime.h>
#include <stdint.h>

#define NN 8192
#define FF 256
#define HH 64

typedef __attribute__((ext_vector_type(8))) short bf16x8;
typedef __attribute__((ext_vector_type(4))) float f32x4;

__device__ __forceinline__ uint16_t f2bf(float f) {
  union { float f; uint32_t i; } c; c.f = f;
  uint32_t r = c.i + 0x7FFFu + ((c.i >> 16) & 1u);
  return (uint16_t)(r >> 16);
}

// ---------------------------------------------------------------------------
// K1 (VERIFIED r5..r13 core): h = x @ Wt^T + bt (fp32), h[node][c].
// Tail zeroes this block's slice of nb_sum (split-K accumulator).
// ---------------------------------------------------------------------------
__global__ __launch_bounds__(256) void k1_h(
    const float* __restrict__ x, const float* __restrict__ Wt,
    const float* __restrict__ bt, float* __restrict__ h,
    float* __restrict__ nb_sum) {
  __shared__ float wtT[256 * 65];
  __shared__ float sbt[64];
  const int t = threadIdx.x;
  const int lane = t & 63;
  const int w = t >> 6;

  for (int i = 0; i < 64; ++i)
    wtT[t * 65 + i] = Wt[(size_t)i * FF + t];
  if (t < 64) sbt[t] = bt[t];
  __syncthreads();

  const int r0 = blockIdx.x * 32 + w * 8;
  const float binit = sbt[lane];
  float acc[8];
#pragma unroll
  for (int r = 0; r < 8; ++r) acc[r] = binit;

  for (int f4 = 0; f4 < FF; f4 += 4) {
    float4 xs[8];
#pragma unroll
    for (int r = 0; r < 8; ++r)
      xs[r] = *(const float4*)(x + (size_t)(r0 + r) * FF + f4);
    const float wt0 = wtT[(f4 + 0) * 65 + lane];
    const float wt1 = wtT[(f4 + 1) * 65 + lane];
    const float wt2 = wtT[(f4 + 2) * 65 + lane];
    const float wt3 = wtT[(f4 + 3) * 65 + lane];
#pragma unroll
    for (int r = 0; r < 8; ++r)
      acc[r] += xs[r].x * wt0 + xs[r].y * wt1 + xs[r].z * wt2 + xs[r].w * wt3;
  }
#pragma unroll
  for (int r = 0; r < 8; ++r)
    h[(size_t)(r0 + r) * HH + lane] = acc[r];

  // zero nb_sum rows 32b..32b+31 (2048 floats = 512 float4)
  float4 z = {0.f, 0.f, 0.f, 0.f};
  float4* nbz = (float4*)(nb_sum + (size_t)blockIdx.x * 32 * HH);
  for (int i = t; i < 512; i += 256) nbz[i] = z;
}

// ---------------------------------------------------------------------------
// K1b (VERIFIED r7..r13, verbatim): hT[c][n] = bf16(h[n][c]). grid=128.
// ---------------------------------------------------------------------------
__global__ __launch_bounds__(256) void k1b_hT(
    const float* __restrict__ h, uint16_t* __restrict__ hT) {
  __shared__ float s[64][65];
  const int t = threadIdx.x;
  const int n0 = blockIdx.x * 64;
  for (int i = 0; i < 16; ++i) {
    int idx = i * 256 + t;
    int r = idx >> 6, c = idx & 63;
    s[r][c] = h[(size_t)(n0 + r) * HH + c];
  }
  __syncthreads();
  for (int i = 0; i < 16; ++i) {
    int idx = i * 256 + t;
    int c = idx >> 6, n = idx & 63;
    hT[(size_t)c * NN + n0 + n] = f2bf(s[n][c]);
  }
}

// ---------------------------------------------------------------------------
// K_pack (new): adj -> bitmask + deg, PURE STRIDE-1 streaming.
// Wave w handles row blockIdx*4+w; lane i reads adj[row][base+i]; one
// __ballot per 64 ints (bit i = lane i = adj[row][base+i]!=0).
// bits[row][w64] covers ks [w64*64, +64). deg = popcount. grid = 2048.
// ---------------------------------------------------------------------------
__global__ __launch_bounds__(256) void k_pack(
    const int* __restrict__ adj, uint64_t* __restrict__ bits,
    int* __restrict__ deg_g) {
  const int t = threadIdx.x;
  const int lane = t & 63;
  const int w = t >> 6;
  const int row = blockIdx.x * 4 + w;
  const int* __restrict__ arow = adj + (size_t)row * NN;
  uint64_t* __restrict__ brow = bits + (size_t)row * (NN / 64);
  int deg = 0;
  for (int base = 0; base < NN; base += 64) {
    int a = arow[base + lane];
    uint64_t b = __ballot(a != 0);
    if (lane == 0) {
      brow[base >> 6] = b;
      deg += __popcll(b);
    }
  }
  if (lane == 0) deg_g[row] = deg;
}

// ---------------------------------------------------------------------------
// K2 = r13 VERIFIED geometry verbatim (BM=16, 4 waves, split-K-2 grid 1024,
// D-store / reduce / nb_sum atomic maps untouched). ONLY change: A-fragment
// built from one 8B bitmask word per row per 64-k (replaces 4 int4 adj
// loads); deg machinery removed (pack computes it).
// ---------------------------------------------------------------------------
__global__ __launch_bounds__(256) void k2_attn(
    const uint64_t* __restrict__ bits, const uint16_t* __restrict__ hT,
    float* __restrict__ nb_sum) {
  __shared__ float s_part[4][16][64];   // 16 KB partial D

  const int t    = threadIdx.x;
  const int w    = t >> 6;
  const int lane = t & 63;
  const int m    = lane & 15;
  const int q    = lane >> 4;
  const int g    = blockIdx.x >> 1;
  const int half = blockIdx.x & 1;
  const int row0 = g * 16;

  const int kbeg = half * (NN / 2) + w * (NN / 8);
  const int kend = kbeg + (NN / 8);

  f32x4 acc0 = 0, acc1 = 0, acc2 = 0, acc3 = 0;
  const uint64_t* __restrict__ brow = bits + (size_t)(row0 + m) * (NN / 64);
  const uint16_t* __restrict__ hrow = hT + (size_t)m * NN;

  for (int kb = kbeg; kb < kend; kb += 64) {
    const int k0 = kb + q * 8;        // chunk A octet
    const int k1 = k0 + 32;           // chunk B octet
    // ---- loads: 1 bitmask word + 8 hT fragments (r13-verbatim B loads) ----
    uint64_t word = brow[kb >> 6];    // bit b = adj[row0+m][kb+b]
    bf16x8 b0 = *(const bf16x8*)(hrow + k0);
    bf16x8 b1 = *(const bf16x8*)(hrow + 16 * NN + k0);
    bf16x8 b2 = *(const bf16x8*)(hrow + 32 * NN + k0);
    bf16x8 b3 = *(const bf16x8*)(hrow + 48 * NN + k0);
    bf16x8 c0 = *(const bf16x8*)(hrow + k1);
    bf16x8 c1 = *(const bf16x8*)(hrow + 16 * NN + k1);
    bf16x8 c2 = *(const bf16x8*)(hrow + 32 * NN + k1);
    bf16x8 c3 = *(const bf16x8*)(hrow + 48 * NN + k1);
    // ---- af from bits: chunk A = bits q*8+j, chunk B = bits 32+q*8+j ----
    const uint32_t byteA = (uint32_t)(word >> (q * 8)) & 0xFFu;
    const uint32_t byteB = (uint32_t)(word >> (q * 8 + 32)) & 0xFFu;
    bf16x8 afA, afB;
    afA[0] = (byteA & 0x01u) ? (short)0x3F80 : (short)0;
    afA[1] = (byteA & 0x02u) ? (short)0x3F80 : (short)0;
    afA[2] = (byteA & 0x04u) ? (short)0x3F80 : (short)0;
    afA[3] = (byteA & 0x08u) ? (short)0x3F80 : (short)0;
    afA[4] = (byteA & 0x10u) ? (short)0x3F80 : (short)0;
    afA[5] = (byteA & 0x20u) ? (short)0x3F80 : (short)0;
    afA[6] = (byteA & 0x40u) ? (short)0x3F80 : (short)0;
    afA[7] = (byteA & 0x80u) ? (short)0x3F80 : (short)0;
    afB[0] = (byteB & 0x01u) ? (short)0x3F80 : (short)0;
    afB[1] = (byteB & 0x02u) ? (short)0x3F80 : (short)0;
    afB[2] = (byteB & 0x04u) ? (short)0x3F80 : (short)0;
    afB[3] = (byteB & 0x08u) ? (short)0x3F80 : (short)0;
    afB[4] = (byteB & 0x10u) ? (short)0x3F80 : (short)0;
    afB[5] = (byteB & 0x20u) ? (short)0x3F80 : (short)0;
    afB[6] = (byteB & 0x40u) ? (short)0x3F80 : (short)0;
    afB[7] = (byteB & 0x80u) ? (short)0x3F80 : (short)0;
    // ---- 8 MFMAs (r13 verbatim) ----
    acc0 = __builtin_amdgcn_mfma_f32_16x16x32_bf16(afA, b0, acc0, 0, 0, 0);
    acc1 = __builtin_amdgcn_mfma_f32_16x16x32_bf16(afA, b1, acc1, 0, 0, 0);
    acc2 = __builtin_amdgcn_mfma_f32_16x16x32_bf16(afA, b2, acc2, 0, 0, 0);
    acc3 = __builtin_amdgcn_mfma_f32_16x16x32_bf16(afA, b3, acc3, 0, 0, 0);
    acc0 = __builtin_amdgcn_mfma_f32_16x16x32_bf16(afB, c0, acc0, 0, 0, 0);
    acc1 = __builtin_amdgcn_mfma_f32_16x16x32_bf16(afB, c1, acc1, 0, 0, 0);
    acc2 = __builtin_amdgcn_mfma_f32_16x16x32_bf16(afB, c2, acc2, 0, 0, 0);
    acc3 = __builtin_amdgcn_mfma_f32_16x16x32_bf16(afB, c3, acc3, 0, 0, 0);
  }

#pragma unroll
  for (int rg = 0; rg < 4; ++rg) {
    s_part[w][q * 4 + rg][ 0 + m] = acc0[rg];
    s_part[w][q * 4 + rg][16 + m] = acc1[rg];
    s_part[w][q * 4 + rg][32 + m] = acc2[rg];
    s_part[w][q * 4 + rg][48 + m] = acc3[rg];
  }
  __syncthreads();

  // cross-wave reduce (r13 verbatim map) -> global atomic accumulate
  for (int idx = t; idx < 16 * 64; idx += 256) {
    int r = idx >> 6, c = idx & 63;
    float s = s_part[0][r][c] + s_part[1][r][c] +
              s_part[2][r][c] + s_part[3][r][c];
    atomicAdd(&nb_sum[(size_t)(row0 + r) * HH + c], s);
  }
}

// ---------------------------------------------------------------------------
// K3 (VERIFIED r13, verbatim): epilogue from nb_sum/deg_g. grid = 512.
// ---------------------------------------------------------------------------
__global__ __launch_bounds__(256) void k3_epi(
    const float* __restrict__ x, const float* __restrict__ nb_sum,
    const int* __restrict__ deg_g, const float* __restrict__ Wp,
    const float* __restrict__ bp, const float* __restrict__ gamma,
    const float* __restrict__ beta, float* __restrict__ out) {
  __shared__ float s_nb[16][64];
  __shared__ float s_y[16 * 256];

  const int t    = threadIdx.x;
  const int w    = t >> 6;
  const int lane = t & 63;
  const int row0 = blockIdx.x * 16;

  for (int idx = t; idx < 16 * 64; idx += 256) {
    int r = idx >> 6, c = idx & 63;
    int d = deg_g[row0 + r];
    float s = nb_sum[(size_t)(row0 + r) * HH + c];
    s_nb[r][c] = (d > 0) ? s / (float)d : 0.f;
  }
  __syncthreads();

  {
    const int f = t;
    float wp[64];
    const float* wrow = Wp + (size_t)f * HH;
#pragma unroll
    for (int j = 0; j < 16; ++j) {
      float4 v = *(const float4*)(wrow + j * 4);
      wp[j * 4 + 0] = v.x; wp[j * 4 + 1] = v.y;
      wp[j * 4 + 2] = v.z; wp[j * 4 + 3] = v.w;
    }
    const float bpf = bp[f];
    for (int r = 0; r < 16; ++r) {
      float a = bpf;
#pragma unroll
      for (int k = 0; k < 64; k += 4) {
        float4 nv = *(const float4*)&s_nb[r][k];
        a += nv.x * wp[k] + nv.y * wp[k + 1] + nv.z * wp[k + 2] + nv.w * wp[k + 3];
      }
      float y = x[(size_t)(row0 + r) * FF + f] + a;
      s_y[r * 256 + f] = y;
    }
  }
  __syncthreads();

  for (int i = 0; i < 4; ++i) {
    const int r = w * 4 + i;
    float4 v = *(const float4*)&s_y[r * 256 + lane * 4];
    float sum = v.x + v.y + v.z + v.w;
    float ss  = v.x * v.x + v.y * v.y + v.z * v.z + v.w * v.w;
#pragma unroll
    for (int o = 32; o >= 1; o >>= 1) {
      sum += __shfl_xor(sum, o, 64);
      ss  += __shfl_xor(ss, o, 64);
    }
    const float mu  = sum * (1.0f / 256.0f);
    const float var = ss * (1.0f / 256.0f) - mu * mu;
    const float rs  = rsqrtf(var + 1e-5f);
    const int f0 = lane * 4;
    float4 g = *(const float4*)(gamma + f0);
    float4 b = *(const float4*)(beta + f0);
    float4 o4;
    o4.x = g.x * (v.x - mu) * rs + b.x;
    o4.y = g.y * (v.y - mu) * rs + b.y;
    o4.z = g.z * (v.z - mu) * rs + b.z;
    o4.w = g.w * (v.w - mu) * rs + b.w;
    *(float4*)(out + (size_t)(row0 + r) * FF + f0) = o4;
  }
}

extern "C" void kernel_launch(void* const* d_in, const int* in_sizes, int n_in,
                              void* d_out, int out_size, void* d_ws, size_t ws_size,
                              hipStream_t stream) {
  const float* x     = (const float*)d_in[0];
  const int*   adj   = (const int*)d_in[1];
  const float* Wt    = (const float*)d_in[2];
  const float* bt    = (const float*)d_in[3];
  // d_in[4] = Wa, d_in[5] = ba: provably dead (softmax scores are row-constant)
  const float* Wp    = (const float*)d_in[6];
  const float* bp    = (const float*)d_in[7];
  const float* gamma = (const float*)d_in[8];
  const float* beta  = (const float*)d_in[9];
  float* out = (float*)d_out;

  // ws layout: hT 1MB | nb_sum 2MB | deg_g 32KB | h 2MB | bits 8MB
  uint16_t* hT     = (uint16_t*)d_ws;
  float*    nb_sum = (float*)((char*)d_ws + (1u << 20));
  int*      deg_g  = (int*)((char*)d_ws + (3u << 20));
  float*    h      = (float*)((char*)d_ws + (3u << 20) + (1u << 18));
  uint64_t* bits   = (uint64_t*)((char*)d_ws + (5u << 20) + (1u << 18));

  k1_h  <<<256, 256, 0, stream>>>(x, Wt, bt, h, nb_sum);
  k1b_hT<<<128, 256, 0, stream>>>(h, hT);
  k_pack<<<2048, 256, 0, stream>>>(adj, bits, deg_g);
  k2_attn<<<1024, 256, 0, stream>>>(bits, hT, nb_sum);
  k3_epi<<<512, 256, 0, stream>>>(x, nb_sum, deg_g, Wp, bp, gamma, beta, out);
}

// Round 15
// 499.586 us; speedup vs baseline: 1.0433x; 1.0433x over previous
//
#include <hip/hip_runtime.h>
#include <stdint.h>

#define NN 8192
#define FF 256
#define HH 64

typedef __attribute__((ext_vector_type(8))) short bf16x8;
typedef __attribute__((ext_vector_type(4))) float f32x4;

__device__ __forceinline__ uint16_t f2bf(float f) {
  union { float f; uint32_t i; } c; c.f = f;
  uint32_t r = c.i + 0x7FFFu + ((c.i >> 16) & 1u);
  return (uint16_t)(r >> 16);
}

// ---------------------------------------------------------------------------
// K1 (VERIFIED r5..r13 core): h = x @ Wt^T + bt (fp32), h[node][c].
// Tail zeroes this block's slice of nb_sum AND deg_g (r13 line restored —
// pack now accumulates deg atomically).
// ---------------------------------------------------------------------------
__global__ __launch_bounds__(256) void k1_h(
    const float* __restrict__ x, const float* __restrict__ Wt,
    const float* __restrict__ bt, float* __restrict__ h,
    float* __restrict__ nb_sum, int* __restrict__ deg_g) {
  __shared__ float wtT[256 * 65];
  __shared__ float sbt[64];
  const int t = threadIdx.x;
  const int lane = t & 63;
  const int w = t >> 6;

  for (int i = 0; i < 64; ++i)
    wtT[t * 65 + i] = Wt[(size_t)i * FF + t];
  if (t < 64) sbt[t] = bt[t];
  __syncthreads();

  const int r0 = blockIdx.x * 32 + w * 8;
  const float binit = sbt[lane];
  float acc[8];
#pragma unroll
  for (int r = 0; r < 8; ++r) acc[r] = binit;

  for (int f4 = 0; f4 < FF; f4 += 4) {
    float4 xs[8];
#pragma unroll
    for (int r = 0; r < 8; ++r)
      xs[r] = *(const float4*)(x + (size_t)(r0 + r) * FF + f4);
    const float wt0 = wtT[(f4 + 0) * 65 + lane];
    const float wt1 = wtT[(f4 + 1) * 65 + lane];
    const float wt2 = wtT[(f4 + 2) * 65 + lane];
    const float wt3 = wtT[(f4 + 3) * 65 + lane];
#pragma unroll
    for (int r = 0; r < 8; ++r)
      acc[r] += xs[r].x * wt0 + xs[r].y * wt1 + xs[r].z * wt2 + xs[r].w * wt3;
  }
#pragma unroll
  for (int r = 0; r < 8; ++r)
    h[(size_t)(r0 + r) * HH + lane] = acc[r];

  // zero nb_sum rows 32b..32b+31 (2048 floats = 512 float4) and deg_g
  float4 z = {0.f, 0.f, 0.f, 0.f};
  float4* nbz = (float4*)(nb_sum + (size_t)blockIdx.x * 32 * HH);
  for (int i = t; i < 512; i += 256) nbz[i] = z;
  if (t < 32) deg_g[blockIdx.x * 32 + t] = 0;
}

// ---------------------------------------------------------------------------
// K1b (VERIFIED r7..r14, verbatim): hT[c][n] = bf16(h[n][c]). grid=128.
// ---------------------------------------------------------------------------
__global__ __launch_bounds__(256) void k1b_hT(
    const float* __restrict__ h, uint16_t* __restrict__ hT) {
  __shared__ float s[64][65];
  const int t = threadIdx.x;
  const int n0 = blockIdx.x * 64;
  for (int i = 0; i < 16; ++i) {
    int idx = i * 256 + t;
    int r = idx >> 6, c = idx & 63;
    s[r][c] = h[(size_t)(n0 + r) * HH + c];
  }
  __syncthreads();
  for (int i = 0; i < 16; ++i) {
    int idx = i * 256 + t;
    int c = idx >> 6, n = idx & 63;
    hT[(size_t)c * NN + n0 + n] = f2bf(s[n][c]);
  }
}

// ---------------------------------------------------------------------------
// K_pack v2: GRID-STRIDE MARCHING WINDOW (the 6.6 TB/s fill/copy pattern).
// 4096 waves step together: at iteration i all waves read the contiguous
// 4 MB window [i*4MB, (i+1)*4MB) of adj. Per 256-elem chunk per wave:
//   lane reads int4 -> 4-bit nibble -> shfl_xor OR-tree builds the four
//   64-bit words in-register -> 4 leader lanes store; deg via popcount +
//   shfl reduce + 1 atomicAdd per chunk.
// Bit semantics IDENTICAL to r14-verified consumer:
//   bits[row][w] bit b = adj[row][w*64+b].
// grid = 1024 x 256.
// ---------------------------------------------------------------------------
__global__ __launch_bounds__(256) void k_pack(
    const int* __restrict__ adj, uint64_t* __restrict__ bits,
    int* __restrict__ deg_g) {
  const int t = threadIdx.x;
  const int lane = t & 63;
  const size_t nchunks = (size_t)NN * NN / 256;     // 262144 chunks
  const int gwaves = gridDim.x * 4;                 // 4096 waves
  const int gw = blockIdx.x * 4 + (t >> 6);         // global wave id

  for (size_t ch = gw; ch < nchunks; ch += gwaves) {
    const size_t e0 = ch * 256;                     // first element of chunk
    const int row  = (int)(e0 >> 13);               // e0 / 8192 (256 | 8192)
    const int col0 = (int)(e0 & 8191);
    int4 a = *(const int4*)(adj + e0 + lane * 4);
    uint64_t nib = (a.x ? 1ull : 0ull) | (a.y ? 2ull : 0ull) |
                   (a.z ? 4ull : 0ull) | (a.w ? 8ull : 0ull);
    uint64_t v = nib << ((lane & 15) * 4);
    // OR-reduce within each aligned 16-lane group -> every lane in group g
    // holds word W_g (covers cols col0 + g*64 .. +63, bit b = col offset b)
    v |= __shfl_xor(v, 1, 64);
    v |= __shfl_xor(v, 2, 64);
    v |= __shfl_xor(v, 4, 64);
    v |= __shfl_xor(v, 8, 64);
    if ((lane & 15) == 0)
      bits[(size_t)row * (NN / 64) + (col0 >> 6) + (lane >> 4)] = v;
    // chunk degree: group leaders hold distinct W_g popcounts; sum to lane 0
    int dg = ((lane & 15) == 0) ? __popcll(v) : 0;
    dg += __shfl_xor(dg, 16, 64);
    dg += __shfl_xor(dg, 32, 64);
    if (lane == 0) atomicAdd(&deg_g[row], dg);
  }
}

// ---------------------------------------------------------------------------
// K2 (VERIFIED r14, verbatim): bits+hT MFMA, r13 geometry (BM=16, 4 waves,
// split-K-2 grid 1024), global atomic nb_sum accumulate.
// ---------------------------------------------------------------------------
__global__ __launch_bounds__(256) void k2_attn(
    const uint64_t* __restrict__ bits, const uint16_t* __restrict__ hT,
    float* __restrict__ nb_sum) {
  __shared__ float s_part[4][16][64];   // 16 KB partial D

  const int t    = threadIdx.x;
  const int w    = t >> 6;
  const int lane = t & 63;
  const int m    = lane & 15;
  const int q    = lane >> 4;
  const int g    = blockIdx.x >> 1;
  const int half = blockIdx.x & 1;
  const int row0 = g * 16;

  const int kbeg = half * (NN / 2) + w * (NN / 8);
  const int kend = kbeg + (NN / 8);

  f32x4 acc0 = 0, acc1 = 0, acc2 = 0, acc3 = 0;
  const uint64_t* __restrict__ brow = bits + (size_t)(row0 + m) * (NN / 64);
  const uint16_t* __restrict__ hrow = hT + (size_t)m * NN;

  for (int kb = kbeg; kb < kend; kb += 64) {
    const int k0 = kb + q * 8;        // chunk A octet
    const int k1 = k0 + 32;           // chunk B octet
    uint64_t word = brow[kb >> 6];    // bit b = adj[row0+m][kb+b]
    bf16x8 b0 = *(const bf16x8*)(hrow + k0);
    bf16x8 b1 = *(const bf16x8*)(hrow + 16 * NN + k0);
    bf16x8 b2 = *(const bf16x8*)(hrow + 32 * NN + k0);
    bf16x8 b3 = *(const bf16x8*)(hrow + 48 * NN + k0);
    bf16x8 c0 = *(const bf16x8*)(hrow + k1);
    bf16x8 c1 = *(const bf16x8*)(hrow + 16 * NN + k1);
    bf16x8 c2 = *(const bf16x8*)(hrow + 32 * NN + k1);
    bf16x8 c3 = *(const bf16x8*)(hrow + 48 * NN + k1);
    const uint32_t byteA = (uint32_t)(word >> (q * 8)) & 0xFFu;
    const uint32_t byteB = (uint32_t)(word >> (q * 8 + 32)) & 0xFFu;
    bf16x8 afA, afB;
    afA[0] = (byteA & 0x01u) ? (short)0x3F80 : (short)0;
    afA[1] = (byteA & 0x02u) ? (short)0x3F80 : (short)0;
    afA[2] = (byteA & 0x04u) ? (short)0x3F80 : (short)0;
    afA[3] = (byteA & 0x08u) ? (short)0x3F80 : (short)0;
    afA[4] = (byteA & 0x10u) ? (short)0x3F80 : (short)0;
    afA[5] = (byteA & 0x20u) ? (short)0x3F80 : (short)0;
    afA[6] = (byteA & 0x40u) ? (short)0x3F80 : (short)0;
    afA[7] = (byteA & 0x80u) ? (short)0x3F80 : (short)0;
    afB[0] = (byteB & 0x01u) ? (short)0x3F80 : (short)0;
    afB[1] = (byteB & 0x02u) ? (short)0x3F80 : (short)0;
    afB[2] = (byteB & 0x04u) ? (short)0x3F80 : (short)0;
    afB[3] = (byteB & 0x08u) ? (short)0x3F80 : (short)0;
    afB[4] = (byteB & 0x10u) ? (short)0x3F80 : (short)0;
    afB[5] = (byteB & 0x20u) ? (short)0x3F80 : (short)0;
    afB[6] = (byteB & 0x40u) ? (short)0x3F80 : (short)0;
    afB[7] = (byteB & 0x80u) ? (short)0x3F80 : (short)0;
    acc0 = __builtin_amdgcn_mfma_f32_16x16x32_bf16(afA, b0, acc0, 0, 0, 0);
    acc1 = __builtin_amdgcn_mfma_f32_16x16x32_bf16(afA, b1, acc1, 0, 0, 0);
    acc2 = __builtin_amdgcn_mfma_f32_16x16x32_bf16(afA, b2, acc2, 0, 0, 0);
    acc3 = __builtin_amdgcn_mfma_f32_16x16x32_bf16(afA, b3, acc3, 0, 0, 0);
    acc0 = __builtin_amdgcn_mfma_f32_16x16x32_bf16(afB, c0, acc0, 0, 0, 0);
    acc1 = __builtin_amdgcn_mfma_f32_16x16x32_bf16(afB, c1, acc1, 0, 0, 0);
    acc2 = __builtin_amdgcn_mfma_f32_16x16x32_bf16(afB, c2, acc2, 0, 0, 0);
    acc3 = __builtin_amdgcn_mfma_f32_16x16x32_bf16(afB, c3, acc3, 0, 0, 0);
  }

#pragma unroll
  for (int rg = 0; rg < 4; ++rg) {
    s_part[w][q * 4 + rg][ 0 + m] = acc0[rg];
    s_part[w][q * 4 + rg][16 + m] = acc1[rg];
    s_part[w][q * 4 + rg][32 + m] = acc2[rg];
    s_part[w][q * 4 + rg][48 + m] = acc3[rg];
  }
  __syncthreads();

  for (int idx = t; idx < 16 * 64; idx += 256) {
    int r = idx >> 6, c = idx & 63;
    float s = s_part[0][r][c] + s_part[1][r][c] +
              s_part[2][r][c] + s_part[3][r][c];
    atomicAdd(&nb_sum[(size_t)(row0 + r) * HH + c], s);
  }
}

// ---------------------------------------------------------------------------
// K3 (VERIFIED r13/r14, verbatim): epilogue from nb_sum/deg_g. grid = 512.
// ---------------------------------------------------------------------------
__global__ __launch_bounds__(256) void k3_epi(
    const float* __restrict__ x, const float* __restrict__ nb_sum,
    const int* __restrict__ deg_g, const float* __restrict__ Wp,
    const float* __restrict__ bp, const float* __restrict__ gamma,
    const float* __restrict__ beta, float* __restrict__ out) {
  __shared__ float s_nb[16][64];
  __shared__ float s_y[16 * 256];

  const int t    = threadIdx.x;
  const int w    = t >> 6;
  const int lane = t & 63;
  const int row0 = blockIdx.x * 16;

  for (int idx = t; idx < 16 * 64; idx += 256) {
    int r = idx >> 6, c = idx & 63;
    int d = deg_g[row0 + r];
    float s = nb_sum[(size_t)(row0 + r) * HH + c];
    s_nb[r][c] = (d > 0) ? s / (float)d : 0.f;
  }
  __syncthreads();

  {
    const int f = t;
    float wp[64];
    const float* wrow = Wp + (size_t)f * HH;
#pragma unroll
    for (int j = 0; j < 16; ++j) {
      float4 v = *(const float4*)(wrow + j * 4);
      wp[j * 4 + 0] = v.x; wp[j * 4 + 1] = v.y;
      wp[j * 4 + 2] = v.z; wp[j * 4 + 3] = v.w;
    }
    const float bpf = bp[f];
    for (int r = 0; r < 16; ++r) {
      float a = bpf;
#pragma unroll
      for (int k = 0; k < 64; k += 4) {
        float4 nv = *(const float4*)&s_nb[r][k];
        a += nv.x * wp[k] + nv.y * wp[k + 1] + nv.z * wp[k + 2] + nv.w * wp[k + 3];
      }
      float y = x[(size_t)(row0 + r) * FF + f] + a;
      s_y[r * 256 + f] = y;
    }
  }
  __syncthreads();

  for (int i = 0; i < 4; ++i) {
    const int r = w * 4 + i;
    float4 v = *(const float4*)&s_y[r * 256 + lane * 4];
    float sum = v.x + v.y + v.z + v.w;
    float ss  = v.x * v.x + v.y * v.y + v.z * v.z + v.w * v.w;
#pragma unroll
    for (int o = 32; o >= 1; o >>= 1) {
      sum += __shfl_xor(sum, o, 64);
      ss  += __shfl_xor(ss, o, 64);
    }
    const float mu  = sum * (1.0f / 256.0f);
    const float var = ss * (1.0f / 256.0f) - mu * mu;
    const float rs  = rsqrtf(var + 1e-5f);
    const int f0 = lane * 4;
    float4 g = *(const float4*)(gamma + f0);
    float4 b = *(const float4*)(beta + f0);
    float4 o4;
    o4.x = g.x * (v.x - mu) * rs + b.x;
    o4.y = g.y * (v.y - mu) * rs + b.y;
    o4.z = g.z * (v.z - mu) * rs + b.z;
    o4.w = g.w * (v.w - mu) * rs + b.w;
    *(float4*)(out + (size_t)(row0 + r) * FF + f0) = o4;
  }
}

extern "C" void kernel_launch(void* const* d_in, const int* in_sizes, int n_in,
                              void* d_out, int out_size, void* d_ws, size_t ws_size,
                              hipStream_t stream) {
  const float* x     = (const float*)d_in[0];
  const int*   adj   = (const int*)d_in[1];
  const float* Wt    = (const float*)d_in[2];
  const float* bt    = (const float*)d_in[3];
  // d_in[4] = Wa, d_in[5] = ba: provably dead (softmax scores are row-constant)
  const float* Wp    = (const float*)d_in[6];
  const float* bp    = (const float*)d_in[7];
  const float* gamma = (const float*)d_in[8];
  const float* beta  = (const float*)d_in[9];
  float* out = (float*)d_out;

  // ws layout: hT 1MB | nb_sum 2MB | deg_g 32KB | h 2MB | bits 8MB
  uint16_t* hT     = (uint16_t*)d_ws;
  float*    nb_sum = (float*)((char*)d_ws + (1u << 20));
  int*      deg_g  = (int*)((char*)d_ws + (3u << 20));
  float*    h      = (float*)((char*)d_ws + (3u << 20) + (1u << 18));
  uint64_t* bits   = (uint64_t*)((char*)d_ws + (5u << 20) + (1u << 18));

  k1_h  <<<256, 256, 0, stream>>>(x, Wt, bt, h, nb_sum, deg_g);
  k1b_hT<<<128, 256, 0, stream>>>(h, hT);
  k_pack<<<1024, 256, 0, stream>>>(adj, bits, deg_g);
  k2_attn<<<1024, 256, 0, stream>>>(bits, hT, nb_sum);
  k3_epi<<<512, 256, 0, stream>>>(x, nb_sum, deg_g, Wp, bp, gamma, beta, out);
}